// Round 4
// baseline (101.196 us; speedup 1.0000x reference)
//
#include <hip/hip_runtime.h>

#define IMG_H 512
#define IMG_W 512
#define N_IMG 24                          // B*C
#define NPIX (N_IMG * IMG_H * IMG_W)      // 6291456
#define ROWS_PB 8                         // output rows per block
#define SROWS 12                          // staged rows = ROWS_PB + 4 halo
#define LDSW 520                          // 2 halo + 512 data + 2 halo + pad (16B-aligned stride)
#define RBLK (IMG_H / ROWS_PB)            // 64 row-blocks per image
#define BLOCK 256
#define NBLOCKS (N_IMG * RBLK)            // 1536
#define NSLOT 16                          // level-1 atomic slots
#define BPS (NBLOCKS / NSLOT)             // 96 blocks per slot

// Branchless reflect for PAD=2 rows: min(|x|, 2H-2-|x|)
__device__ __forceinline__ int reflect_b(int x) {
    int a = x < 0 ? -x : x;
    int b = 2 * IMG_H - 2 - a;
    return a < b ? a : b;
}

// Load one window row (8 floats per input) from LDS. Window col x lives at
// lds idx x+2, so the 8-wide window for output quad w0 starts at idx w0:
// byte offset = r*2080 + 16*sc  -> 16B-aligned ds_read_b128, lane stride 16B
// (contiguous across the wave: conflict-free).
#define ROW_LD(K)                                                      \
    {                                                                  \
        const int r_ = sl4 + (K);                                      \
        const float4 a_ = *(const float4*)&lds[0][r_][c4];             \
        const float4 b_ = *(const float4*)&lds[0][r_][c4 + 4];         \
        pw[K][0] = a_.x; pw[K][1] = a_.y; pw[K][2] = a_.z; pw[K][3] = a_.w; \
        pw[K][4] = b_.x; pw[K][5] = b_.y; pw[K][6] = b_.z; pw[K][7] = b_.w; \
        const float4 c_ = *(const float4*)&lds[1][r_][c4];             \
        const float4 d_ = *(const float4*)&lds[1][r_][c4 + 4];         \
        gw[K][0] = c_.x; gw[K][1] = c_.y; gw[K][2] = c_.z; gw[K][3] = c_.w; \
        gw[K][4] = d_.x; gw[K][5] = d_.y; gw[K][6] = d_.z; gw[K][7] = d_.w; \
    }

// Per-lane census compare (proven formulation: 2 v_cmp + addc per element).
#define DO_ROW(R)                                                              \
    {                                                                          \
        const float pc0 = pw[(R) + 2][2], pc1 = pw[(R) + 2][3],                \
                    pc2 = pw[(R) + 2][4], pc3 = pw[(R) + 2][5];                \
        const float gc0 = gw[(R) + 2][2], gc1 = gw[(R) + 2][3],                \
                    gc2 = gw[(R) + 2][4], gc3 = gw[(R) + 2][5];                \
        _Pragma("unroll")                                                      \
        for (int dy = 0; dy < 5; ++dy) {                                       \
            const int row = (R) + dy;                                          \
            _Pragma("unroll")                                                  \
            for (int dx = 0; dx < 5; ++dx) {                                   \
                if (dy == 2 && dx == 2) continue;                              \
                c0 += (int)((pw[row][0 + dx] < pc0) != (gw[row][0 + dx] < gc0)); \
                c1 += (int)((pw[row][1 + dx] < pc1) != (gw[row][1 + dx] < gc1)); \
                c2 += (int)((pw[row][2 + dx] < pc2) != (gw[row][2 + dx] < gc2)); \
                c3 += (int)((pw[row][3 + dx] < pc3) != (gw[row][3 + dx] < gc3)); \
            }                                                                  \
        }                                                                      \
    }

// Zero the 17 u64 accumulator slots (ws is poisoned by the harness each iter).
__global__ __launch_bounds__(64, 1) void census_init(unsigned long long* ws64) {
    if (threadIdx.x < NSLOT + 1) ws64[threadIdx.x] = 0ull;
}

__global__ __launch_bounds__(BLOCK, 3) void census_main(
    const float* __restrict__ pred, const float* __restrict__ gt,
    float* __restrict__ out, unsigned long long* __restrict__ ws64)
{
    // XCD-chunked swizzle: consecutive logical blocks (vertically adjacent
    // tiles sharing 4 halo rows) land on the same XCD's L2. 1536 % 8 == 0.
    const int b   = blockIdx.x;
    const int n   = (b & 7) * (NBLOCKS / 8) + (b >> 3);
    const int img = n >> 6;                 // n / RBLK
    const int rb  = n & (RBLK - 1);
    const int h0  = rb * ROWS_PB;

    const float* __restrict__ pimg = pred + (size_t)img * IMG_H * IMG_W;
    const float* __restrict__ gimg = gt   + (size_t)img * IMG_H * IMG_W;

    // LDS tile: [input][staged row][2 halo | 512 data | 2 halo | 4 pad]
    __shared__ float lds[2][SROWS][LDSW];   // 49,920 B -> 3 blocks/CU

    // ---- cooperative staging: 12 rows x 512 cols x 2 inputs ----
    {
        const int q  = threadIdx.x & 127;
        const int rg = threadIdx.x >> 7;
        #pragma unroll
        for (int i = 0; i < 6; ++i) {
            const int lr = rg + 2 * i;
            const int gy = reflect_b(h0 - 2 + lr);
            const float4 pv = *(const float4*)(pimg + (size_t)gy * IMG_W + 4 * q);
            const float4 gv = *(const float4*)(gimg + (size_t)gy * IMG_W + 4 * q);
            // dest idx 2+4q -> byte 8 mod 16: write as two float2 (8B-aligned)
            *(float2*)&lds[0][lr][2 + 4 * q] = make_float2(pv.x, pv.y);
            *(float2*)&lds[0][lr][4 + 4 * q] = make_float2(pv.z, pv.w);
            *(float2*)&lds[1][lr][2 + 4 * q] = make_float2(gv.x, gv.y);
            *(float2*)&lds[1][lr][4 + 4 * q] = make_float2(gv.z, gv.w);
        }
    }

    // ---- bake horizontal reflect halo (96 scalar loads, hit L2) ----
    if (threadIdx.x < 96) {
        const int r = threadIdx.x >> 3;         // 0..11
        const int i = (threadIdx.x >> 2) & 1;   // input
        const int c = threadIdx.x & 3;          // halo slot
        const int srccol = (c == 0) ? 2 : (c == 1) ? 1 : (c == 2) ? 510 : 509;
        const int dst    = (c == 0) ? 0 : (c == 1) ? 1 : (c == 2) ? 514 : 515;
        const int gy = reflect_b(h0 - 2 + r);
        const float* base = i ? gimg : pimg;
        lds[i][r][dst] = base[(size_t)gy * IMG_W + srccol];
    }
    __syncthreads();

    // ---- compute: thread = 4 cols x 4 rows ----
    const int sc  = threadIdx.x & 127;      // col quad (consecutive lanes)
    const int sl  = threadIdx.x >> 7;       // row half (0/1)
    const int c4  = 4 * sc;                 // window start idx in LDS row
    const int sl4 = 4 * sl;                 // first window row in LDS

    float pw[8][8], gw[8][8];
    int c0 = 0, c1 = 0, c2 = 0, c3 = 0;

    ROW_LD(0) ROW_LD(1) ROW_LD(2) ROW_LD(3) ROW_LD(4)
    DO_ROW(0)
    ROW_LD(5) DO_ROW(1)
    ROW_LD(6) DO_ROW(2)
    ROW_LD(7) DO_ROW(3)

    int cnt = (c0 + c1) + (c2 + c3);

    // ---- block reduction (exact integer) ----
    #pragma unroll
    for (int off = 32; off > 0; off >>= 1)
        cnt += __shfl_down(cnt, off, 64);

    __shared__ int wave_sums[BLOCK / 64];
    const int lane = threadIdx.x & 63;
    const int wid  = threadIdx.x >> 6;
    if (lane == 0) wave_sums[wid] = cnt;
    __syncthreads();

    // ---- fused hierarchical finalize: u64 packed {count:32 | sum:32} ----
    // One RMW carries ticket AND data -> no fence, no ordering hazard, exact.
    // Level 1: 16 slots x 96 blocks (separate cachelines, low contention).
    // Level 2: 1 slot x 16 adds. Last arriver computes the mean.
    if (threadIdx.x == 0) {
        const unsigned int total =
            (unsigned int)(wave_sums[0] + wave_sums[1] +
                           wave_sums[2] + wave_sums[3]);
        const unsigned long long pack = (1ull << 32) | (unsigned long long)total;
        const unsigned long long old = atomicAdd(&ws64[b & (NSLOT - 1)], pack);
        if ((unsigned int)(old >> 32) == BPS - 1) {          // last in slot
            const unsigned int slotsum = (unsigned int)old + total;
            const unsigned long long old2 =
                atomicAdd(&ws64[NSLOT],
                          (1ull << 32) | (unsigned long long)slotsum);
            if ((unsigned int)(old2 >> 32) == NSLOT - 1) {   // last slot done
                const unsigned int tot = (unsigned int)old2 + slotsum;
                out[0] = (float)((double)tot / (double)NPIX);
            }
        }
    }
}

extern "C" void kernel_launch(void* const* d_in, const int* in_sizes, int n_in,
                              void* d_out, int out_size, void* d_ws, size_t ws_size,
                              hipStream_t stream) {
    const float* pred      = (const float*)d_in[0];
    const float* gt        = (const float*)d_in[1];
    float* out             = (float*)d_out;
    unsigned long long* ws = (unsigned long long*)d_ws;  // needs 17*8 = 136 B

    census_init<<<1, 64, 0, stream>>>(ws);
    census_main<<<NBLOCKS, BLOCK, 0, stream>>>(pred, gt, out, ws);
}